// Round 15
// baseline (173.432 us; speedup 1.0000x reference)
//
#include <hip/hip_runtime.h>

// Mixture-of-64-tiny-experts, fp32.
// R14: single change vs R12 — weight fetch moved from the SCALAR path
// (s_load; 96 floats/iter ~ fills the SGPR file -> no cross-iteration
// prefetch -> per-iter lgkmcnt stall-wall, the suspected invariant behind
// R4..R13 all landing at ~72us) to the VECTOR path: each subnet-pair block
// stored twice, indexed by (tid&1)*96 -> genuinely per-lane address ->
// global_load_dwordx4 broadcast, vmcnt-tracked, deep prefetch under compute.

#define NSUB 64
#define L2E  1.4426950408889634f   // log2(e)
#define L2E2 2.8853900817779268f   // 2*log2(e)

typedef float v2f __attribute__((ext_vector_type(2)));

__device__ __forceinline__ v2f pk_fma(v2f a, v2f b, v2f c) {
    return __builtin_elementwise_fma(a, b, c);
}
__device__ __forceinline__ v2f sp(float s) { return v2f{s, s}; }

// packed reciprocal: magic seed + one packed Newton step. rel err ~8.8e-4.
__device__ __forceinline__ v2f pk_rcp_nr(v2f d) {
    v2f r;
    r.x = __int_as_float(0x7EF312AC - __float_as_int(d.x));
    r.y = __int_as_float(0x7EF312AC - __float_as_int(d.y));
    v2f c = sp(2.0f) - d * r;
    return r * c;
}

// packed tanhshrink(a) = (a-1) + 2*rcp(exp2(2L*a)+1)
__device__ __forceinline__ v2f tanhshrink_v(v2f a) {
    v2f s = a * L2E2;
    v2f e;
    e.x = __builtin_amdgcn_exp2f(s.x);
    e.y = __builtin_amdgcn_exp2f(s.y);
    v2f r = pk_rcp_nr(e + 1.0f);
    return pk_fma(sp(2.0f), r, a - 1.0f);
}

// packed tanh from pre-scaled input s = 2*log2e*raw: 1 - 2*rcp(exp2(s)+1)
__device__ __forceinline__ v2f tanh_scaled_v(v2f s) {
    v2f e;
    e.x = __builtin_amdgcn_exp2f(s.x);
    e.y = __builtin_amdgcn_exp2f(s.y);
    v2f r = pk_rcp_nr(e + 1.0f);
    return pk_fma(sp(-2.0f), r, sp(1.0f));
}

// scalar tanhshrink for the gating net
__device__ __forceinline__ float tanhshrink_s(float a) {
    float e = __builtin_amdgcn_exp2f(a * L2E2);
    float r = __builtin_amdgcn_rcpf(e + 1.0f);
    return fmaf(2.0f, r, a - 1.0f);
}

// Pack per subnet-PAIR p (p, p+32): 192 floats = TWO identical 96-float
// copies (48 v2f slots each). Slot layout within a copy:
// [0:24) W1 pairs (j*6+i) | [24:28) b1 | [28:36) W2*2L (o*4+j) | [36:38) b2*2L
// [38:44) Gw2*L | [44] Gb2*L | [45:48) pad
__global__ void pack_kernel(const float* __restrict__ W1, const float* __restrict__ b1,
                            const float* __restrict__ W2, const float* __restrict__ b2,
                            const float* __restrict__ Gw2, const float* __restrict__ Gb2,
                            float* __restrict__ ws)
{
    int p = threadIdx.x;
    if (p >= 32) return;
    int sa = p, sb = p + 32;
    float* f = ws + p * 192;
    for (int i = 0; i < 24; ++i) { f[2*i]   = W1[sa*24+i];        f[2*i+1]   = W1[sb*24+i]; }
    for (int i = 0; i < 4;  ++i) { f[48+2*i] = b1[sa*4+i];        f[48+2*i+1] = b1[sb*4+i]; }
    for (int i = 0; i < 8;  ++i) { f[56+2*i] = W2[sa*8+i]*L2E2;   f[56+2*i+1] = W2[sb*8+i]*L2E2; }
    for (int i = 0; i < 2;  ++i) { f[72+2*i] = b2[sa*2+i]*L2E2;   f[72+2*i+1] = b2[sb*2+i]*L2E2; }
    for (int i = 0; i < 6;  ++i) { f[76+2*i] = Gw2[sa*6+i]*L2E;   f[76+2*i+1] = Gw2[sb*6+i]*L2E; }
    f[88] = Gb2[sa]*L2E; f[89] = Gb2[sb]*L2E;
    f[90] = 0.f; f[91] = 0.f; f[92] = 0.f; f[93] = 0.f; f[94] = 0.f; f[95] = 0.f;
    for (int i = 0; i < 96; ++i) f[96 + i] = f[i];   // duplicate copy
}

__global__ __launch_bounds__(256) void moe_kernel(
    const float* __restrict__ x,
    const float* __restrict__ wpack,
    const float* __restrict__ Gw1, const float* __restrict__ Gb1,
    float* __restrict__ out)
{
    long t = blockIdx.x * blockDim.x + threadIdx.x;

    // per-lane duplicate-copy selector: genuinely non-uniform -> forces the
    // weight loads onto the vector-memory path (global_load + L1 broadcast)
    int dup = (threadIdx.x & 1) * 96;

    // two samples per thread: 12 floats = 3 x float4
    const float4* xv = (const float4*)(x + t * 12);
    float4 q0 = xv[0];
    float4 q1 = xv[1];
    float4 q2 = xv[2];
    float xsA[6] = {q0.x, q0.y, q0.z, q0.w, q1.x, q1.y};
    float xsB[6] = {q1.z, q1.w, q2.x, q2.y, q2.z, q2.w};

    // ---- gating hidden per sample (scalar) ----
    float gaA[6], gaB[6];
#pragma unroll
    for (int j = 0; j < 6; ++j) {
        float sA = Gb1[j], sB = sA;
#pragma unroll
        for (int i = 0; i < 6; ++i) {
            float w = Gw1[j * 6 + i];
            sA = fmaf(w, xsA[i], sA);
            sB = fmaf(w, xsB[i], sB);
        }
        gaA[j] = tanhshrink_s(sA);
        gaB[j] = tanhshrink_s(sB);
    }

    v2f xaA[6], xaB[6], gbA[6], gbB[6];
#pragma unroll
    for (int i = 0; i < 6; ++i) { xaA[i] = sp(xsA[i]); xaB[i] = sp(xsB[i]); }
#pragma unroll
    for (int j = 0; j < 6; ++j) { gbA[j] = sp(gaA[j]); gbB[j] = sp(gaB[j]); }

    v2f acc0A = sp(0.f), acc1A = sp(0.f), accEA = sp(0.f);
    v2f acc0B = sp(0.f), acc1B = sp(0.f), accEB = sp(0.f);

#pragma unroll 2
    for (int p = 0; p < 32; ++p) {
        const v2f* f2 = (const v2f*)(wpack + p * 192 + dup);  // vector loads

        v2f hA[4], hB[4];
#pragma unroll
        for (int j = 0; j < 4; ++j) {
            v2f w0 = f2[j * 6 + 0];
            v2f bb = f2[24 + j];
            v2f sA = pk_fma(w0, xaA[0], bb);
            v2f sB = pk_fma(w0, xaB[0], bb);
#pragma unroll
            for (int i = 1; i < 6; ++i) {
                v2f w = f2[j * 6 + i];
                sA = pk_fma(w, xaA[i], sA);
                sB = pk_fma(w, xaB[i], sB);
            }
            hA[j] = tanhshrink_v(sA);
            hB[j] = tanhshrink_v(sB);
        }

        v2f o0A, o0B, o1A, o1B;
        {
            v2f w28 = f2[28], w29 = f2[29], w30 = f2[30], w31 = f2[31], b0 = f2[36];
            o0A = pk_fma(w28, hA[0], b0);  o0B = pk_fma(w28, hB[0], b0);
            o0A = pk_fma(w29, hA[1], o0A); o0B = pk_fma(w29, hB[1], o0B);
            o0A = pk_fma(w30, hA[2], o0A); o0B = pk_fma(w30, hB[2], o0B);
            o0A = pk_fma(w31, hA[3], o0A); o0B = pk_fma(w31, hB[3], o0B);
            o0A = tanh_scaled_v(o0A);      o0B = tanh_scaled_v(o0B);
        }
        {
            v2f w32 = f2[32], w33 = f2[33], w34 = f2[34], w35 = f2[35], b1v = f2[37];
            o1A = pk_fma(w32, hA[0], b1v); o1B = pk_fma(w32, hB[0], b1v);
            o1A = pk_fma(w33, hA[1], o1A); o1B = pk_fma(w33, hB[1], o1B);
            o1A = pk_fma(w34, hA[2], o1A); o1B = pk_fma(w34, hB[2], o1B);
            o1A = pk_fma(w35, hA[3], o1A); o1B = pk_fma(w35, hB[3], o1B);
            o1A = tanh_scaled_v(o1A);      o1B = tanh_scaled_v(o1B);
        }

        v2f laA, laB;
        {
            v2f g0 = f2[38], g1 = f2[39], g2 = f2[40], g3 = f2[41], g4 = f2[42],
                g5 = f2[43], gb = f2[44];
            laA = pk_fma(g0, gbA[0], gb);  laB = pk_fma(g0, gbB[0], gb);
            laA = pk_fma(g1, gbA[1], laA); laB = pk_fma(g1, gbB[1], laB);
            laA = pk_fma(g2, gbA[2], laA); laB = pk_fma(g2, gbB[2], laB);
            laA = pk_fma(g3, gbA[3], laA); laB = pk_fma(g3, gbB[3], laB);
            laA = pk_fma(g4, gbA[4], laA); laB = pk_fma(g4, gbB[4], laB);
            laA = pk_fma(g5, gbA[5], laA); laB = pk_fma(g5, gbB[5], laB);
        }
        v2f eA, eB;
        eA.x = __builtin_amdgcn_exp2f(laA.x);
        eA.y = __builtin_amdgcn_exp2f(laA.y);
        eB.x = __builtin_amdgcn_exp2f(laB.x);
        eB.y = __builtin_amdgcn_exp2f(laB.y);

        accEA = accEA + eA;             accEB = accEB + eB;
        acc0A = pk_fma(eA, o0A, acc0A); acc0B = pk_fma(eB, o0B, acc0B);
        acc1A = pk_fma(eA, o1A, acc1A); acc1B = pk_fma(eB, o1B, acc1B);
    }

    float EA = accEA.x + accEA.y;
    float EB = accEB.x + accEB.y;
    float rA = __builtin_amdgcn_rcpf(EA);
    float rB = __builtin_amdgcn_rcpf(EB);
    float4 res;
    res.x = (acc0A.x + acc0A.y) * rA;
    res.y = (acc1A.x + acc1A.y) * rA;
    res.z = (acc0B.x + acc0B.y) * rB;
    res.w = (acc1B.x + acc1B.y) * rB;
    ((float4*)&out[t * 4])[0] = res;
}

extern "C" void kernel_launch(void* const* d_in, const int* in_sizes, int n_in,
                              void* d_out, int out_size, void* d_ws, size_t ws_size,
                              hipStream_t stream) {
    const float* x   = (const float*)d_in[0];
    const float* W1  = (const float*)d_in[1];
    const float* b1  = (const float*)d_in[2];
    const float* W2  = (const float*)d_in[3];
    const float* b2  = (const float*)d_in[4];
    const float* Gw1 = (const float*)d_in[5];
    const float* Gb1 = (const float*)d_in[6];
    const float* Gw2 = (const float*)d_in[7];
    const float* Gb2 = (const float*)d_in[8];
    float* out = (float*)d_out;
    float* ws  = (float*)d_ws;   // 32*192*4 = 24 KB

    pack_kernel<<<1, 64, 0, stream>>>(W1, b1, W2, b2, Gw2, Gb2, ws);

    // 2 samples/thread -> 262144 threads -> 1024 blocks
    const int threads = 256;
    const int blocks = (524288 / 2) / threads;  // 1024
    moe_kernel<<<blocks, threads, 0, stream>>>(x, ws, Gw1, Gb1, out);
}

// Round 16
// 69.316 us; speedup vs baseline: 2.5021x; 2.5021x over previous
//
#include <hip/hip_runtime.h>

// Mixture-of-64-tiny-experts, fp32.
// R15: dual-chain ILP at max hardware occupancy. Evidence: all flat rounds
// share (waves/SIMD) x (indep chains/wave) = 8; time never tracked inst
// count, fetch bytes, or memory path -> dependent-latency-bound with fixed
// hiding capacity. This round: R9 structure (1 sample/thread, 8 waves/SIMD,
// s_load weights) but 16 iterations x TWO independent subnet-pair chains
// (pairs q and q+16), private accumulators, merged at the end -> 16 streams
// per SIMD, double every prior config.

#define NSUB 64
#define L2E  1.4426950408889634f   // log2(e)
#define L2E2 2.8853900817779268f   // 2*log2(e)

typedef float v2f __attribute__((ext_vector_type(2)));

__device__ __forceinline__ v2f pk_fma(v2f a, v2f b, v2f c) {
    return __builtin_elementwise_fma(a, b, c);
}
__device__ __forceinline__ v2f sp(float s) { return v2f{s, s}; }

// packed reciprocal: magic seed + one packed Newton step. rel err ~8.8e-4.
__device__ __forceinline__ v2f pk_rcp_nr(v2f d) {
    v2f r;
    r.x = __int_as_float(0x7EF312AC - __float_as_int(d.x));
    r.y = __int_as_float(0x7EF312AC - __float_as_int(d.y));
    v2f c = sp(2.0f) - d * r;
    return r * c;
}

// packed tanhshrink(a) = (a-1) + 2*rcp(exp2(2L*a)+1)
__device__ __forceinline__ v2f tanhshrink_v(v2f a) {
    v2f s = a * L2E2;
    v2f e;
    e.x = __builtin_amdgcn_exp2f(s.x);
    e.y = __builtin_amdgcn_exp2f(s.y);
    v2f r = pk_rcp_nr(e + 1.0f);
    return pk_fma(sp(2.0f), r, a - 1.0f);
}

// packed tanh from pre-scaled input s = 2*log2e*raw: 1 - 2*rcp(exp2(s)+1)
__device__ __forceinline__ v2f tanh_scaled_v(v2f s) {
    v2f e;
    e.x = __builtin_amdgcn_exp2f(s.x);
    e.y = __builtin_amdgcn_exp2f(s.y);
    v2f r = pk_rcp_nr(e + 1.0f);
    return pk_fma(sp(-2.0f), r, sp(1.0f));
}

// scalar tanhshrink for the once-per-thread gating net
__device__ __forceinline__ float tanhshrink_s(float a) {
    float e = __builtin_amdgcn_exp2f(a * L2E2);
    float r = __builtin_amdgcn_rcpf(e + 1.0f);
    return fmaf(2.0f, r, a - 1.0f);
}

// Pack per subnet-PAIR p (p, p+32), 96 floats = 48 v2f slots (R9 layout):
// [0:24) W1 pairs (j*6+i) | [24:28) b1 | [28:36) W2*2L (o*4+j) | [36:38) b2*2L
// [38:44) Gw2*L | [44] Gb2*L | [45:48) pad
__global__ void pack_kernel(const float* __restrict__ W1, const float* __restrict__ b1,
                            const float* __restrict__ W2, const float* __restrict__ b2,
                            const float* __restrict__ Gw2, const float* __restrict__ Gb2,
                            float* __restrict__ ws)
{
    int p = threadIdx.x;
    if (p >= 32) return;
    int sa = p, sb = p + 32;
    float* f = ws + p * 96;
    for (int i = 0; i < 24; ++i) { f[2*i]   = W1[sa*24+i];        f[2*i+1]   = W1[sb*24+i]; }
    for (int i = 0; i < 4;  ++i) { f[48+2*i] = b1[sa*4+i];        f[48+2*i+1] = b1[sb*4+i]; }
    for (int i = 0; i < 8;  ++i) { f[56+2*i] = W2[sa*8+i]*L2E2;   f[56+2*i+1] = W2[sb*8+i]*L2E2; }
    for (int i = 0; i < 2;  ++i) { f[72+2*i] = b2[sa*2+i]*L2E2;   f[72+2*i+1] = b2[sb*2+i]*L2E2; }
    for (int i = 0; i < 6;  ++i) { f[76+2*i] = Gw2[sa*6+i]*L2E;   f[76+2*i+1] = Gw2[sb*6+i]*L2E; }
    f[88] = Gb2[sa]*L2E; f[89] = Gb2[sb]*L2E;
    f[90] = 0.f; f[91] = 0.f; f[92] = 0.f; f[93] = 0.f; f[94] = 0.f; f[95] = 0.f;
}

// one subnet-pair chain step for one sample; returns via accumulator refs
__device__ __forceinline__ void chain_step(const v2f* __restrict__ f2,
                                           const v2f* __restrict__ xa,
                                           const v2f* __restrict__ gab,
                                           v2f& acc0, v2f& acc1, v2f& accE)
{
    v2f h[4];
#pragma unroll
    for (int j = 0; j < 4; ++j) {
        v2f s = pk_fma(f2[j * 6 + 0], xa[0], f2[24 + j]);
#pragma unroll
        for (int i = 1; i < 6; ++i)
            s = pk_fma(f2[j * 6 + i], xa[i], s);
        h[j] = tanhshrink_v(s);
    }

    v2f o0 = pk_fma(f2[28], h[0], f2[36]);   // W2,b2 pre-scaled by 2*log2e
    o0 = pk_fma(f2[29], h[1], o0);
    o0 = pk_fma(f2[30], h[2], o0);
    o0 = pk_fma(f2[31], h[3], o0);
    o0 = tanh_scaled_v(o0);

    v2f o1 = pk_fma(f2[32], h[0], f2[37]);
    o1 = pk_fma(f2[33], h[1], o1);
    o1 = pk_fma(f2[34], h[2], o1);
    o1 = pk_fma(f2[35], h[3], o1);
    o1 = tanh_scaled_v(o1);

    v2f la = pk_fma(f2[38], gab[0], f2[44]); // Gw2,Gb2 pre-scaled by log2e
    la = pk_fma(f2[39], gab[1], la);
    la = pk_fma(f2[40], gab[2], la);
    la = pk_fma(f2[41], gab[3], la);
    la = pk_fma(f2[42], gab[4], la);
    la = pk_fma(f2[43], gab[5], la);
    v2f ea;
    ea.x = __builtin_amdgcn_exp2f(la.x);
    ea.y = __builtin_amdgcn_exp2f(la.y);

    accE = accE + ea;
    acc0 = pk_fma(ea, o0, acc0);
    acc1 = pk_fma(ea, o1, acc1);
}

__global__ __launch_bounds__(256) void moe_kernel(
    const float* __restrict__ x,
    const float* __restrict__ wpack,
    const float* __restrict__ Gw1, const float* __restrict__ Gb1,
    float* __restrict__ out)
{
    long t = blockIdx.x * blockDim.x + threadIdx.x;

    // one sample: 6 floats, 24B stride -> three float2 loads
    const float2* xv = (const float2*)(x + t * 6);
    float2 p0 = xv[0];
    float2 p1 = xv[1];
    float2 p2 = xv[2];
    float xs[6] = {p0.x, p0.y, p1.x, p1.y, p2.x, p2.y};

    // ---- gating hidden (scalar, once per thread) ----
    float ga[6];
#pragma unroll
    for (int j = 0; j < 6; ++j) {
        float s = Gb1[j];
#pragma unroll
        for (int i = 0; i < 6; ++i)
            s = fmaf(Gw1[j * 6 + i], xs[i], s);
        ga[j] = tanhshrink_s(s);
    }

    v2f xa[6], gab[6];
#pragma unroll
    for (int i = 0; i < 6; ++i) xa[i] = sp(xs[i]);
#pragma unroll
    for (int j = 0; j < 6; ++j) gab[j] = sp(ga[j]);

    // ---- TWO independent chains: pairs q (subnets q,q+32) and q+16 ----
    v2f acc0X = sp(0.f), acc1X = sp(0.f), accEX = sp(0.f);
    v2f acc0Y = sp(0.f), acc1Y = sp(0.f), accEY = sp(0.f);

#pragma unroll 2
    for (int q = 0; q < 16; ++q) {
        const v2f* fX = (const v2f*)(wpack + q * 96);
        const v2f* fY = (const v2f*)(wpack + (q + 16) * 96);
        chain_step(fX, xa, gab, acc0X, acc1X, accEX);
        chain_step(fY, xa, gab, acc0Y, acc1Y, accEY);
    }

    // merge chains, then cross-half reduction (x:=s<32-half, y:=s>=32-half)
    v2f accE = accEX + accEY;
    v2f acc0 = acc0X + acc0Y;
    v2f acc1 = acc1X + acc1Y;

    float E  = accE.x + accE.y;
    float r  = __builtin_amdgcn_rcpf(E);
    float u0 = (acc0.x + acc0.y) * r;
    float u1 = (acc1.x + acc1.y) * r;
    float2 res; res.x = u0; res.y = u1;
    ((float2*)&out[t * 2])[0] = res;
}

extern "C" void kernel_launch(void* const* d_in, const int* in_sizes, int n_in,
                              void* d_out, int out_size, void* d_ws, size_t ws_size,
                              hipStream_t stream) {
    const float* x   = (const float*)d_in[0];
    const float* W1  = (const float*)d_in[1];
    const float* b1  = (const float*)d_in[2];
    const float* W2  = (const float*)d_in[3];
    const float* b2  = (const float*)d_in[4];
    const float* Gw1 = (const float*)d_in[5];
    const float* Gb1 = (const float*)d_in[6];
    const float* Gw2 = (const float*)d_in[7];
    const float* Gb2 = (const float*)d_in[8];
    float* out = (float*)d_out;
    float* ws  = (float*)d_ws;   // 32*96*4 = 12 KB

    pack_kernel<<<1, 64, 0, stream>>>(W1, b1, W2, b2, Gw2, Gb2, ws);

    // 1 sample/thread -> 524288 threads -> 2048 blocks (8 waves/SIMD = HW max)
    const int threads = 256;
    const int blocks = 524288 / threads;  // 2048
    moe_kernel<<<blocks, threads, 0, stream>>>(x, ws, Gw1, Gb1, out);
}

// Round 17
// 68.480 us; speedup vs baseline: 2.5326x; 1.0122x over previous
//
#include <hip/hip_runtime.h>

// Mixture-of-64-tiny-experts, fp32.
// R16: algebraic folds. Cost model (retrofits ALL rounds): scalar=2cyc,
// pk_f32=4cyc, trans=8cyc, issue-bound at ~78% VALUBusy. Folds delete
// instructions outright (exact math, no new error):
//  1) 2*log2e folded into W1,b1 -> L1 emits s'=2L*s (kills 4 scale-muls)
//  2) tanhshrink tail folded into L2: h = s'/2L - 1 + 2u, u=rcp(exp2(s')+1),
//     via W2s=W2, W2u=4L*W2, b2''=2L*(b2-sum(W2)) (kills 4 fma+4 sub, +8 fma)
//  3) output tanh folded into softmax accum: sum gate*tanh = 1-2*(sum ea*u)/E
//  4) hw v_rcp (drop NR: equal cost, less error)
// Structure = R9/R15: 1 sample/thread, subnet-pair v2f, 8 waves/SIMD, s_load.

#define NSUB 64
#define L2E  1.4426950408889634f   // log2(e)
#define L2E2 2.8853900817779268f   // 2*log2(e)

typedef float v2f __attribute__((ext_vector_type(2)));

__device__ __forceinline__ v2f pk_fma(v2f a, v2f b, v2f c) {
    return __builtin_elementwise_fma(a, b, c);
}
__device__ __forceinline__ v2f sp(float s) { return v2f{s, s}; }

// u = rcp(exp2(z)+1), both halves. Overflow-safe: z->+inf => u->0, z->-inf => u->1.
__device__ __forceinline__ v2f sig_u(v2f z) {
    v2f e;
    e.x = __builtin_amdgcn_exp2f(z.x);
    e.y = __builtin_amdgcn_exp2f(z.y);
    v2f ep = e + 1.0f;
    v2f u;
    u.x = __builtin_amdgcn_rcpf(ep.x);
    u.y = __builtin_amdgcn_rcpf(ep.y);
    return u;
}

// scalar tanhshrink for the once-per-thread gating net
__device__ __forceinline__ float tanhshrink_s(float a) {
    float e = __builtin_amdgcn_exp2f(a * L2E2);
    float r = __builtin_amdgcn_rcpf(e + 1.0f);
    return fmaf(2.0f, r, a - 1.0f);
}

// Pack per subnet-PAIR p (p, p+32), stride 128 floats = 64 v2f slots:
// [0:24)  W1' = 2L*W1 (j*6+i)     [24:28) b1' = 2L*b1
// [28:36) W2s = W2 (o*4+j)        [36:44) W2u = 4L*W2 (o*4+j)
// [44:46) b2'' = 2L*(b2 - sum_j W2[o][j])
// [46:52) Gw2*L                   [52] Gb2*L        [53:64) pad
__global__ void pack_kernel(const float* __restrict__ W1, const float* __restrict__ b1,
                            const float* __restrict__ W2, const float* __restrict__ b2,
                            const float* __restrict__ Gw2, const float* __restrict__ Gb2,
                            float* __restrict__ ws)
{
    int p = threadIdx.x;
    if (p >= 32) return;
    int sa = p, sb = p + 32;
    float* f = ws + p * 128;
    for (int i = 0; i < 24; ++i) { f[2*i]   = W1[sa*24+i]*L2E2;  f[2*i+1]   = W1[sb*24+i]*L2E2; }
    for (int i = 0; i < 4;  ++i) { f[48+2*i] = b1[sa*4+i]*L2E2;  f[48+2*i+1] = b1[sb*4+i]*L2E2; }
    for (int i = 0; i < 8;  ++i) { f[56+2*i] = W2[sa*8+i];       f[56+2*i+1] = W2[sb*8+i]; }
    for (int i = 0; i < 8;  ++i) { f[72+2*i] = W2[sa*8+i]*(2.0f*L2E2);
                                   f[72+2*i+1] = W2[sb*8+i]*(2.0f*L2E2); }
    for (int o = 0; o < 2; ++o) {
        float rsA = 0.f, rsB = 0.f;
        for (int j = 0; j < 4; ++j) { rsA += W2[sa*8+o*4+j]; rsB += W2[sb*8+o*4+j]; }
        f[88+2*o]   = (b2[sa*2+o] - rsA) * L2E2;
        f[88+2*o+1] = (b2[sb*2+o] - rsB) * L2E2;
    }
    for (int i = 0; i < 6;  ++i) { f[92+2*i] = Gw2[sa*6+i]*L2E;  f[92+2*i+1] = Gw2[sb*6+i]*L2E; }
    f[104] = Gb2[sa]*L2E; f[105] = Gb2[sb]*L2E;
    for (int i = 106; i < 128; ++i) f[i] = 0.f;
}

__global__ __launch_bounds__(256) void moe_kernel(
    const float* __restrict__ x,
    const float* __restrict__ wpack,
    const float* __restrict__ Gw1, const float* __restrict__ Gb1,
    float* __restrict__ out)
{
    long t = blockIdx.x * blockDim.x + threadIdx.x;

    // one sample: 6 floats, 24B stride -> three float2 loads
    const float2* xv = (const float2*)(x + t * 6);
    float2 p0 = xv[0];
    float2 p1 = xv[1];
    float2 p2 = xv[2];
    float xs[6] = {p0.x, p0.y, p1.x, p1.y, p2.x, p2.y};

    // ---- gating hidden (scalar, once per thread) ----
    float ga[6];
#pragma unroll
    for (int j = 0; j < 6; ++j) {
        float s = Gb1[j];
#pragma unroll
        for (int i = 0; i < 6; ++i)
            s = fmaf(Gw1[j * 6 + i], xs[i], s);
        ga[j] = tanhshrink_s(s);
    }

    v2f xa[6], gab[6];
#pragma unroll
    for (int i = 0; i < 6; ++i) xa[i] = sp(xs[i]);
#pragma unroll
    for (int j = 0; j < 6; ++j) gab[j] = sp(ga[j]);

    // ---- 32 iterations; v2f halves cover subnets p and p+32 ----
    v2f accE = sp(0.f), accU0 = sp(0.f), accU1 = sp(0.f);

#pragma unroll 2
    for (int p = 0; p < 32; ++p) {
        const v2f* f2 = (const v2f*)(wpack + p * 128);   // 64 subnet-pair slots

        // layer-1 pre-scaled preacts s' = 2L*(W1 x + b1)
        v2f s0 = pk_fma(f2[0],  xa[0], f2[24]);
        v2f s1 = pk_fma(f2[6],  xa[0], f2[25]);
        v2f s2 = pk_fma(f2[12], xa[0], f2[26]);
        v2f s3 = pk_fma(f2[18], xa[0], f2[27]);
#pragma unroll
        for (int i = 1; i < 6; ++i) {
            s0 = pk_fma(f2[i],      xa[i], s0);
            s1 = pk_fma(f2[6 + i],  xa[i], s1);
            s2 = pk_fma(f2[12 + i], xa[i], s2);
            s3 = pk_fma(f2[18 + i], xa[i], s3);
        }

        // u_j = rcp(exp2(s'_j)+1); tanhshrink folded into L2 weights
        v2f u0 = sig_u(s0);
        v2f u1 = sig_u(s1);
        v2f u2 = sig_u(s2);
        v2f u3 = sig_u(s3);

        // layer-2: o' = 2L*o_real = W2s.s' + W2u.u + b2''
        v2f q0 = pk_fma(f2[28], s0, f2[44]);
        q0 = pk_fma(f2[29], s1, q0);
        q0 = pk_fma(f2[30], s2, q0);
        q0 = pk_fma(f2[31], s3, q0);
        q0 = pk_fma(f2[36], u0, q0);
        q0 = pk_fma(f2[37], u1, q0);
        q0 = pk_fma(f2[38], u2, q0);
        q0 = pk_fma(f2[39], u3, q0);

        v2f q1 = pk_fma(f2[32], s0, f2[45]);
        q1 = pk_fma(f2[33], s1, q1);
        q1 = pk_fma(f2[34], s2, q1);
        q1 = pk_fma(f2[35], s3, q1);
        q1 = pk_fma(f2[40], u0, q1);
        q1 = pk_fma(f2[41], u1, q1);
        q1 = pk_fma(f2[42], u2, q1);
        q1 = pk_fma(f2[43], u3, q1);

        // output sigmoids: tanh(o) = 1 - 2*uo, tanh folded into accumulation
        v2f uo0 = sig_u(q0);
        v2f uo1 = sig_u(q1);

        // gate logit (pre-scaled by log2e) -> exp2
        v2f la = pk_fma(f2[46], gab[0], f2[52]);
        la = pk_fma(f2[47], gab[1], la);
        la = pk_fma(f2[48], gab[2], la);
        la = pk_fma(f2[49], gab[3], la);
        la = pk_fma(f2[50], gab[4], la);
        la = pk_fma(f2[51], gab[5], la);
        v2f ea;
        ea.x = __builtin_amdgcn_exp2f(la.x);
        ea.y = __builtin_amdgcn_exp2f(la.y);

        accE  = accE + ea;
        accU0 = pk_fma(ea, uo0, accU0);
        accU1 = pk_fma(ea, uo1, accU1);
    }

    // out_o = sum gate*tanh(o) = 1 - 2*(sum ea*uo)/E   (cross-half reduced)
    float E  = accE.x + accE.y;
    float r  = __builtin_amdgcn_rcpf(E);
    float U0 = accU0.x + accU0.y;
    float U1 = accU1.x + accU1.y;
    float2 res;
    res.x = fmaf(-2.0f * U0, r, 1.0f);
    res.y = fmaf(-2.0f * U1, r, 1.0f);
    ((float2*)&out[t * 2])[0] = res;
}

extern "C" void kernel_launch(void* const* d_in, const int* in_sizes, int n_in,
                              void* d_out, int out_size, void* d_ws, size_t ws_size,
                              hipStream_t stream) {
    const float* x   = (const float*)d_in[0];
    const float* W1  = (const float*)d_in[1];
    const float* b1  = (const float*)d_in[2];
    const float* W2  = (const float*)d_in[3];
    const float* b2  = (const float*)d_in[4];
    const float* Gw1 = (const float*)d_in[5];
    const float* Gb1 = (const float*)d_in[6];
    const float* Gw2 = (const float*)d_in[7];
    const float* Gb2 = (const float*)d_in[8];
    float* out = (float*)d_out;
    float* ws  = (float*)d_ws;   // 32*128*4 = 16 KB

    pack_kernel<<<1, 64, 0, stream>>>(W1, b1, W2, b2, Gw2, Gb2, ws);

    // 1 sample/thread -> 524288 threads -> 2048 blocks (8 waves/SIMD)
    const int threads = 256;
    const int blocks = 524288 / threads;  // 2048
    moe_kernel<<<blocks, threads, 0, stream>>>(x, ws, Gw1, Gb1, out);
}

// Round 18
// 64.575 us; speedup vs baseline: 2.6857x; 1.0605x over previous
//
#include <hip/hip_runtime.h>

// Mixture-of-64-tiny-experts, fp32.
// R17: combine the two measured minima (both 68.4us): R16's folded math
// (56 pk + 26 trans per iter — fewest instructions of any round) x R12's
// 2-samples-per-thread (weight fetch amortized 2x, two independent chains).
// Gating net now also packed (pair = the two samples). Last additive move;
// if flat, the 68us basin is the HIP-level floor (inst-rate bound ~6cyc/inst).

#define NSUB 64
#define L2E  1.4426950408889634f   // log2(e)
#define L2E2 2.8853900817779268f   // 2*log2(e)

typedef float v2f __attribute__((ext_vector_type(2)));

__device__ __forceinline__ v2f pk_fma(v2f a, v2f b, v2f c) {
    return __builtin_elementwise_fma(a, b, c);
}
__device__ __forceinline__ v2f sp(float s) { return v2f{s, s}; }

// u = rcp(exp2(z)+1), both halves. Overflow-safe at +-inf.
__device__ __forceinline__ v2f sig_u(v2f z) {
    v2f e;
    e.x = __builtin_amdgcn_exp2f(z.x);
    e.y = __builtin_amdgcn_exp2f(z.y);
    v2f ep = e + 1.0f;
    v2f u;
    u.x = __builtin_amdgcn_rcpf(ep.x);
    u.y = __builtin_amdgcn_rcpf(ep.y);
    return u;
}

// Pack per subnet-PAIR p (p, p+32), stride 128 floats = 64 v2f slots
// (R16 layout):
// [0:24)  W1' = 2L*W1 (j*6+i)     [24:28) b1' = 2L*b1
// [28:36) W2s = W2 (o*4+j)        [36:44) W2u = 4L*W2 (o*4+j)
// [44:46) b2'' = 2L*(b2 - sum_j W2[o][j])
// [46:52) Gw2*L                   [52] Gb2*L        [53:64) pad
__global__ void pack_kernel(const float* __restrict__ W1, const float* __restrict__ b1,
                            const float* __restrict__ W2, const float* __restrict__ b2,
                            const float* __restrict__ Gw2, const float* __restrict__ Gb2,
                            float* __restrict__ ws)
{
    int p = threadIdx.x;
    if (p >= 32) return;
    int sa = p, sb = p + 32;
    float* f = ws + p * 128;
    for (int i = 0; i < 24; ++i) { f[2*i]   = W1[sa*24+i]*L2E2;  f[2*i+1]   = W1[sb*24+i]*L2E2; }
    for (int i = 0; i < 4;  ++i) { f[48+2*i] = b1[sa*4+i]*L2E2;  f[48+2*i+1] = b1[sb*4+i]*L2E2; }
    for (int i = 0; i < 8;  ++i) { f[56+2*i] = W2[sa*8+i];       f[56+2*i+1] = W2[sb*8+i]; }
    for (int i = 0; i < 8;  ++i) { f[72+2*i] = W2[sa*8+i]*(2.0f*L2E2);
                                   f[72+2*i+1] = W2[sb*8+i]*(2.0f*L2E2); }
    for (int o = 0; o < 2; ++o) {
        float rsA = 0.f, rsB = 0.f;
        for (int j = 0; j < 4; ++j) { rsA += W2[sa*8+o*4+j]; rsB += W2[sb*8+o*4+j]; }
        f[88+2*o]   = (b2[sa*2+o] - rsA) * L2E2;
        f[88+2*o+1] = (b2[sb*2+o] - rsB) * L2E2;
    }
    for (int i = 0; i < 6;  ++i) { f[92+2*i] = Gw2[sa*6+i]*L2E;  f[92+2*i+1] = Gw2[sb*6+i]*L2E; }
    f[104] = Gb2[sa]*L2E; f[105] = Gb2[sb]*L2E;
    for (int i = 106; i < 128; ++i) f[i] = 0.f;
}

// One subnet-pair step for one sample (R16 folded math).
__device__ __forceinline__ void step(const v2f* __restrict__ f2,
                                     const v2f* __restrict__ xa,
                                     const v2f* __restrict__ gab,
                                     v2f& accE, v2f& accU0, v2f& accU1)
{
    // layer-1 pre-scaled preacts s' = 2L*(W1 x + b1)
    v2f s0 = pk_fma(f2[0],  xa[0], f2[24]);
    v2f s1 = pk_fma(f2[6],  xa[0], f2[25]);
    v2f s2 = pk_fma(f2[12], xa[0], f2[26]);
    v2f s3 = pk_fma(f2[18], xa[0], f2[27]);
#pragma unroll
    for (int i = 1; i < 6; ++i) {
        s0 = pk_fma(f2[i],      xa[i], s0);
        s1 = pk_fma(f2[6 + i],  xa[i], s1);
        s2 = pk_fma(f2[12 + i], xa[i], s2);
        s3 = pk_fma(f2[18 + i], xa[i], s3);
    }

    v2f u0 = sig_u(s0);
    v2f u1 = sig_u(s1);
    v2f u2 = sig_u(s2);
    v2f u3 = sig_u(s3);

    // layer-2: o' = 2L*o = W2s.s' + W2u.u + b2''  (tanhshrink folded in)
    v2f q0 = pk_fma(f2[28], s0, f2[44]);
    q0 = pk_fma(f2[29], s1, q0);
    q0 = pk_fma(f2[30], s2, q0);
    q0 = pk_fma(f2[31], s3, q0);
    q0 = pk_fma(f2[36], u0, q0);
    q0 = pk_fma(f2[37], u1, q0);
    q0 = pk_fma(f2[38], u2, q0);
    q0 = pk_fma(f2[39], u3, q0);

    v2f q1 = pk_fma(f2[32], s0, f2[45]);
    q1 = pk_fma(f2[33], s1, q1);
    q1 = pk_fma(f2[34], s2, q1);
    q1 = pk_fma(f2[35], s3, q1);
    q1 = pk_fma(f2[40], u0, q1);
    q1 = pk_fma(f2[41], u1, q1);
    q1 = pk_fma(f2[42], u2, q1);
    q1 = pk_fma(f2[43], u3, q1);

    v2f uo0 = sig_u(q0);          // tanh(o) = 1 - 2*uo, folded into epilogue
    v2f uo1 = sig_u(q1);

    // gate logit (pre-scaled by log2e) -> exp2
    v2f la = pk_fma(f2[46], gab[0], f2[52]);
    la = pk_fma(f2[47], gab[1], la);
    la = pk_fma(f2[48], gab[2], la);
    la = pk_fma(f2[49], gab[3], la);
    la = pk_fma(f2[50], gab[4], la);
    la = pk_fma(f2[51], gab[5], la);
    v2f ea;
    ea.x = __builtin_amdgcn_exp2f(la.x);
    ea.y = __builtin_amdgcn_exp2f(la.y);

    accE  = accE + ea;
    accU0 = pk_fma(ea, uo0, accU0);
    accU1 = pk_fma(ea, uo1, accU1);
}

__global__ __launch_bounds__(256) void moe_kernel(
    const float* __restrict__ x,
    const float* __restrict__ wpack,
    const float* __restrict__ Gw1, const float* __restrict__ Gb1,
    float* __restrict__ out)
{
    long t = blockIdx.x * blockDim.x + threadIdx.x;

    // two samples per thread: 12 floats = 3 x float4 (48B stride, aligned)
    const float4* xv = (const float4*)(x + t * 12);
    float4 v0 = xv[0];
    float4 v1 = xv[1];
    float4 v2 = xv[2];
    float xsA[6] = {v0.x, v0.y, v0.z, v0.w, v1.x, v1.y};
    float xsB[6] = {v1.z, v1.w, v2.x, v2.y, v2.z, v2.w};

    // ---- gating hidden, PACKED over the two samples: pair = (A, B) ----
    v2f xp[6];
#pragma unroll
    for (int i = 0; i < 6; ++i) xp[i] = v2f{xsA[i], xsB[i]};

    v2f g[6];
#pragma unroll
    for (int j = 0; j < 6; ++j) {
        v2f s = sp(Gb1[j]);
#pragma unroll
        for (int i = 0; i < 6; ++i)
            s = pk_fma(sp(Gw1[j * 6 + i]), xp[i], s);
        v2f u = sig_u(s * L2E2);
        g[j] = pk_fma(sp(2.0f), u, s - 1.0f);   // tanhshrink
    }

    // per-sample broadcasts for the subnet loop (halves = subnet pair)
    v2f xaA[6], xaB[6], gbA[6], gbB[6];
#pragma unroll
    for (int i = 0; i < 6; ++i) { xaA[i] = sp(xsA[i]); xaB[i] = sp(xsB[i]); }
#pragma unroll
    for (int j = 0; j < 6; ++j) { gbA[j] = sp(g[j].x); gbB[j] = sp(g[j].y); }

    v2f accEA = sp(0.f), U0A = sp(0.f), U1A = sp(0.f);
    v2f accEB = sp(0.f), U0B = sp(0.f), U1B = sp(0.f);

#pragma unroll 2
    for (int p = 0; p < 32; ++p) {
        const v2f* f2 = (const v2f*)(wpack + p * 128);   // one fetch, 2 samples
        step(f2, xaA, gbA, accEA, U0A, U1A);
        step(f2, xaB, gbB, accEB, U0B, U1B);
    }

    // out_o = 1 - 2*(sum ea*uo)/E per sample (cross-half reduced)
    float EA = accEA.x + accEA.y;
    float EB = accEB.x + accEB.y;
    float rA = __builtin_amdgcn_rcpf(EA);
    float rB = __builtin_amdgcn_rcpf(EB);
    float4 res;
    res.x = fmaf(-2.0f * (U0A.x + U0A.y), rA, 1.0f);
    res.y = fmaf(-2.0f * (U1A.x + U1A.y), rA, 1.0f);
    res.z = fmaf(-2.0f * (U0B.x + U0B.y), rB, 1.0f);
    res.w = fmaf(-2.0f * (U1B.x + U1B.y), rB, 1.0f);
    ((float4*)&out[t * 4])[0] = res;
}

extern "C" void kernel_launch(void* const* d_in, const int* in_sizes, int n_in,
                              void* d_out, int out_size, void* d_ws, size_t ws_size,
                              hipStream_t stream) {
    const float* x   = (const float*)d_in[0];
    const float* W1  = (const float*)d_in[1];
    const float* b1  = (const float*)d_in[2];
    const float* W2  = (const float*)d_in[3];
    const float* b2  = (const float*)d_in[4];
    const float* Gw1 = (const float*)d_in[5];
    const float* Gb1 = (const float*)d_in[6];
    const float* Gw2 = (const float*)d_in[7];
    const float* Gb2 = (const float*)d_in[8];
    float* out = (float*)d_out;
    float* ws  = (float*)d_ws;   // 32*128*4 = 16 KB

    pack_kernel<<<1, 64, 0, stream>>>(W1, b1, W2, b2, Gw2, Gb2, ws);

    // 2 samples/thread -> 262144 threads -> 1024 blocks
    const int threads = 256;
    const int blocks = (524288 / 2) / threads;  // 1024
    moe_kernel<<<blocks, threads, 0, stream>>>(x, ws, Gw1, Gb1, out);
}